// Round 5
// baseline (328.885 us; speedup 1.0000x reference)
//
#include <hip/hip_runtime.h>

typedef _Float16 half8 __attribute__((ext_vector_type(8)));
typedef float f32x4 __attribute__((ext_vector_type(4)));

#define B_ 256
#define K_ 512
#define D_ 256
#define H_ 256
#define NROWS (B_*K_)          // 131072
#define LNEPS 1e-5f
#define NBLK 256               // one block per batch row; 1 block/CU
#define ITERS 16               // 16 tiles of 32 rows = 512 rows = 1 batch
#define INV1024 (1.0f/1024.0f)

// LDS layout (dynamic):
//   [0,65536)       A h/l double buffer (2 x (16KB h + 16KB l))
//   [65536,69632)   red double buffer: float [2][512]  (stride 512 floats!)
//   [69632,73728)   gum: float [512][2]  (precomputed gumbel noise)
//   [73728,75776)   rkb: uint [512]      (rand_key bits)
#define LDS_BYTES 75776

__global__ __launch_bounds__(512, 2) void mfma_main(
    const float* __restrict__ slots, const float* __restrict__ gamma,
    const float* __restrict__ beta,  const float* __restrict__ w1,
    const float* __restrict__ b1,    const float* __restrict__ w2,
    const float* __restrict__ b2,    const float* __restrict__ u,
    const float* __restrict__ rk,
    float* __restrict__ out)
{
    extern __shared__ __align__(16) char smem[];
    float*    redb = (float*)(smem + 65536);     // [2][512], stride 512
    float*    gum  = (float*)(smem + 69632);     // [512][2]
    unsigned* rkb  = (unsigned*)(smem + 73728);  // [512]

    const int t    = threadIdx.x;
    const int lane = t & 63;
    const int wv   = t >> 6;        // 0..7
    const int quad = lane >> 4;     // 0..3
    const int n16  = lane & 15;
    const int srow = t >> 4;        // 0..31 staging row
    const int seg  = t & 15;        // 16 d's per staging thread
    const int swzr = srow & 7;
    const int swzn = n16 & 7;
    const int cb   = wv * 32;
    const int r0row = blockIdx.x * 512;   // block == batch row blockIdx.x

    // ---- one-time: gumbel noise + rand-key bits into LDS ----
    {
        const float2 uu = ((const float2*)u)[r0row + t];
        gum[2*t + 0] = -logf(-logf(uu.x));
        gum[2*t + 1] = -logf(-logf(uu.y));
        rkb[t] = __float_as_uint(rk[r0row + t]);
    }

    // ---- persistent B fragments: B[k=quad*8+j][n] (h + scaled low) ----
    half8 Bh[2][8], Bl[2][8];
    #pragma unroll
    for (int ct = 0; ct < 2; ++ct) {
        const int col = cb + ct*16 + n16;
        #pragma unroll
        for (int ks = 0; ks < 8; ++ks) {
            const int k0 = ks*32 + quad*8;
            half8 h, l;
            #pragma unroll
            for (int j = 0; j < 8; ++j) {
                const float w = w1[(size_t)(k0 + j)*H_ + col];
                const _Float16 hh = (_Float16)w;
                h[j] = hh;
                l[j] = (_Float16)((w - (float)hh) * 1024.0f);
            }
            Bh[ct][ks] = h; Bl[ct][ks] = l;
        }
    }
    // epilogue constants
    float b1v[2], w20[2], w21[2];
    #pragma unroll
    for (int ct = 0; ct < 2; ++ct) {
        const int col = cb + ct*16 + n16;
        b1v[ct] = b1[col]; w20[ct] = w2[col*2]; w21[ct] = w2[col*2+1];
    }
    // hoisted gamma/beta (per staging seg)
    float gv[16], bv[16];
    {
        const float4* gp = (const float4*)(gamma + seg*16);
        const float4* bp = (const float4*)(beta  + seg*16);
        #pragma unroll
        for (int i4 = 0; i4 < 4; ++i4) {
            const float4 g4 = gp[i4], b4 = bp[i4];
            gv[4*i4+0]=g4.x; gv[4*i4+1]=g4.y; gv[4*i4+2]=g4.z; gv[4*i4+3]=g4.w;
            bv[4*i4+0]=b4.x; bv[4*i4+1]=b4.y; bv[4*i4+2]=b4.z; bv[4*i4+3]=b4.w;
        }
    }

    const int tile0 = blockIdx.x * ITERS;

    // LN + fp16 split + swizzled LDS store of one 32-row tile
    auto ln_stage = [&](const float* xr, char* AhW, char* AlW) {
        float s = 0.f;
        #pragma unroll
        for (int j = 0; j < 16; ++j) s += xr[j];
        s += __shfl_xor(s, 1, 64); s += __shfl_xor(s, 2, 64);
        s += __shfl_xor(s, 4, 64); s += __shfl_xor(s, 8, 64);
        const float mean = s * (1.f/256.f);
        float q = 0.f;
        #pragma unroll
        for (int j = 0; j < 16; ++j) { const float d = xr[j]-mean; q += d*d; }
        q += __shfl_xor(q, 1, 64); q += __shfl_xor(q, 2, 64);
        q += __shfl_xor(q, 4, 64); q += __shfl_xor(q, 8, 64);
        const float rstd = rsqrtf(q * (1.f/256.f) + LNEPS);
        #pragma unroll
        for (int b = 0; b < 2; ++b) {
            half8 hh, ll;
            #pragma unroll
            for (int jj = 0; jj < 8; ++jj) {
                const int idx = b*8 + jj;
                const float x = (xr[idx]-mean)*rstd*gv[idx] + bv[idx];
                const _Float16 xh = (_Float16)x;
                hh[jj] = xh;
                ll[jj] = (_Float16)((x - (float)xh) * 1024.0f);
            }
            const int gW = ((2*seg + b) ^ swzr) * 16;
            *(half8*)(AhW + srow*512 + gW) = hh;
            *(half8*)(AlW + srow*512 + gW) = ll;
        }
    };

    // prologue: stage tile0 into buffer 0
    {
        const float* sp = slots + ((size_t)tile0*32 + srow)*D_ + seg*16;
        float xr[16];
        #pragma unroll
        for (int i4 = 0; i4 < 4; ++i4) {
            const float4 v = ((const float4*)sp)[i4];
            xr[4*i4+0]=v.x; xr[4*i4+1]=v.y; xr[4*i4+2]=v.z; xr[4*i4+3]=v.w;
        }
        ln_stage(xr, smem, smem + 16384);
    }
    __syncthreads();

    int kcnt = 0;                         // wave-0 fixup state
    unsigned long long bestall = 0;

    for (int i = 0; i < ITERS; ++i) {
        const int p = i & 1;
        const bool have_next = (i + 1 < ITERS);

        // early global prefetch for next tile (latency hidden by MFMA phase)
        float xr[16];
        if (have_next) {
            const float* sp = slots + ((size_t)(tile0+i+1)*32 + srow)*D_ + seg*16;
            #pragma unroll
            for (int i4 = 0; i4 < 4; ++i4) {
                const float4 v = ((const float4*)sp)[i4];
                xr[4*i4+0]=v.x; xr[4*i4+1]=v.y; xr[4*i4+2]=v.z; xr[4*i4+3]=v.w;
            }
        }

        // ---- MFMA: 3-pass split over K=256 ----
        const char* Ah = smem + (size_t)p*32768;
        const char* Al = Ah + 16384;
        f32x4 Ch[2][2], Cl[2][2];
        #pragma unroll
        for (int rs = 0; rs < 2; ++rs)
            #pragma unroll
            for (int ct = 0; ct < 2; ++ct) { Ch[rs][ct] = (f32x4)0.f; Cl[rs][ct] = (f32x4)0.f; }

        #pragma unroll
        for (int ks = 0; ks < 8; ++ks) {
            const int go = ((ks*4 + quad) ^ swzn) * 16;
            const half8 ah0 = *(const half8*)(Ah +  n16     *512 + go);
            const half8 ah1 = *(const half8*)(Ah + (n16+16) *512 + go);
            const half8 al0 = *(const half8*)(Al +  n16     *512 + go);
            const half8 al1 = *(const half8*)(Al + (n16+16) *512 + go);
            #pragma unroll
            for (int ct = 0; ct < 2; ++ct) {
                Ch[0][ct] = __builtin_amdgcn_mfma_f32_16x16x32_f16(ah0, Bh[ct][ks], Ch[0][ct], 0,0,0);
                Ch[1][ct] = __builtin_amdgcn_mfma_f32_16x16x32_f16(ah1, Bh[ct][ks], Ch[1][ct], 0,0,0);
                Cl[0][ct] = __builtin_amdgcn_mfma_f32_16x16x32_f16(ah0, Bl[ct][ks], Cl[0][ct], 0,0,0);
                Cl[1][ct] = __builtin_amdgcn_mfma_f32_16x16x32_f16(ah1, Bl[ct][ks], Cl[1][ct], 0,0,0);
                Cl[0][ct] = __builtin_amdgcn_mfma_f32_16x16x32_f16(al0, Bh[ct][ks], Cl[0][ct], 0,0,0);
                Cl[1][ct] = __builtin_amdgcn_mfma_f32_16x16x32_f16(al1, Bh[ct][ks], Cl[1][ct], 0,0,0);
            }
        }

        // ---- stage next tile (overlaps with other waves' MFMA/LDS stream) ----
        if (have_next) {
            char* AhW = smem + (size_t)(p^1)*32768;
            ln_stage(xr, AhW, AhW + 16384);
        }

        // ---- epilogue: relu + w2 dot -> 16 partials, butterfly reduce ----
        float val[16];
        #pragma unroll
        for (int rs = 0; rs < 2; ++rs) {
            #pragma unroll
            for (int reg = 0; reg < 4; ++reg) {
                float p0 = 0.f, p1 = 0.f;
                #pragma unroll
                for (int ct = 0; ct < 2; ++ct) {
                    float hv = Ch[rs][ct][reg] + Cl[rs][ct][reg]*INV1024 + b1v[ct];
                    hv = fmaxf(hv, 0.f);
                    p0 = fmaf(hv, w20[ct], p0);
                    p1 = fmaf(hv, w21[ct], p1);
                }
                val[rs*4 + reg]     = p0;
                val[8 + rs*4 + reg] = p1;
            }
        }
        // value-splitting butterfly over the 16 n16-lanes: 15 shfl total.
        // Final: lane n16 holds reduced val-index n16.
        int c = 16;
        #pragma unroll
        for (int o = 8; o >= 1; o >>= 1) {
            const int hf = c >> 1;
            const bool hi = (n16 & o) != 0;
            #pragma unroll
            for (int j = 0; j < 8; ++j) {
                if (j < hf) {
                    const float send = hi ? val[j] : val[j + hf];
                    const float recv = __shfl_xor(send, o, 64);
                    val[j] = (hi ? val[j + hf] : val[j]) + recv;
                }
            }
            c = hf;
        }
        {
            const int ch  = n16 >> 3;
            const int rs  = (n16 >> 2) & 1;
            const int reg = n16 & 3;
            const int row = rs*16 + quad*4 + reg;
            redb[p*512 + (wv*32 + row)*2 + ch] = val[0];
        }
        __syncthreads();

        // ---- finalize (wave 0 only; overlaps other waves' next iteration) ----
        if (wv == 0) {
            bool keep = false;
            unsigned long long comb = 0;
            if (lane < 32) {
                const float* rp = redb + p*512;
                float l0 = b2[0], l1 = b2[1];
                #pragma unroll
                for (int w = 0; w < 8; ++w) {
                    l0 += rp[(w*32 + lane)*2 + 0];
                    l1 += rp[(w*32 + lane)*2 + 1];
                }
                const int lrow = i*32 + lane;          // row within batch
                const int gr = r0row + lrow;
                const float g0 = gum[2*lrow + 0];
                const float g1 = gum[2*lrow + 1];
                keep = (l1 + g1) > (l0 + g0);
                out[gr] = keep ? 1.f : 0.f;
                out[NROWS + gr] = 1.f / (1.f + expf(l0 - l1));
                if (!keep)
                    comb = ((unsigned long long)rkb[lrow] << 32) | (unsigned)(K_ - 1 - lrow);
            }
            kcnt += __popcll(__ballot(keep));
            #pragma unroll
            for (int off = 32; off >= 1; off >>= 1) {
                const unsigned long long o = __shfl_xor(comb, off, 64);
                if (o > comb) comb = o;
            }
            if (comb > bestall) bestall = comb;
        }
    }

    // ---- fused lower-bound fixup (block == one batch row) ----
    if (t == 0 && kcnt == 0) {
        __threadfence();   // order after this wave's earlier mask stores
        const int kbest = (K_ - 1) - (int)(bestall & 0xffffffffu);
        out[r0row + kbest] = 1.f;
    }
}

extern "C" void kernel_launch(void* const* d_in, const int* in_sizes, int n_in,
                              void* d_out, int out_size, void* d_ws, size_t ws_size,
                              hipStream_t stream) {
    const float* slots = (const float*)d_in[0];
    const float* gamma = (const float*)d_in[1];
    const float* beta  = (const float*)d_in[2];
    const float* w1    = (const float*)d_in[3];
    const float* b1    = (const float*)d_in[4];
    const float* w2    = (const float*)d_in[5];
    const float* b2    = (const float*)d_in[6];
    const float* u     = (const float*)d_in[7];
    const float* rk    = (const float*)d_in[8];
    float* out = (float*)d_out;

    hipLaunchKernelGGL(mfma_main, dim3(NBLK), dim3(512), LDS_BYTES, stream,
                       slots, gamma, beta, w1, b1, w2, b2, u, rk, out);
}

// Round 6
// 271.493 us; speedup vs baseline: 1.2114x; 1.2114x over previous
//
#include <hip/hip_runtime.h>

typedef _Float16 half8 __attribute__((ext_vector_type(8)));
typedef float f32x4 __attribute__((ext_vector_type(4)));

#define B_ 256
#define K_ 512
#define D_ 256
#define H_ 256
#define NROWS (B_*K_)          // 131072
#define LNEPS 1e-5f
#define ITERS 16               // row-tiles of 32 per block pair
#define INV1024 (1.0f/1024.0f)

// Main: 512 blocks (pair = bid>>1 owns rows [pair*512,+512); half = bid&1
// owns cols [half*128,+128)). 512 thr = 8 waves x 16 cols. B-frags (gamma-
// folded fp16 h+l) = 64 VGPRs/wave, persistent. A tile (32 rows xhat h/l)
// double-buffered in LDS. Partial (p0,p1) per row -> ws as float2.
// LDS: 2 x 32768 A + 2048 red = 67584 B -> 2 blocks/CU, 16 waves/CU.
#define LDS_BYTES (65536 + 2048)

__global__ __launch_bounds__(512, 4) void mfma_main(
    const float* __restrict__ slots, const float* __restrict__ gamma,
    const float* __restrict__ beta,  const float* __restrict__ w1,
    const float* __restrict__ b1,    const float* __restrict__ w2,
    float* __restrict__ ws)
{
    extern __shared__ __align__(16) char smem[];
    float2* red = (float2*)(smem + 65536);       // [8][32]

    const int t    = threadIdx.x;
    const int lane = t & 63;
    const int wv   = t >> 6;        // 0..7
    const int quad = lane >> 4;     // 0..3
    const int n16  = lane & 15;
    const int srow = t >> 4;        // 0..31 staging row
    const int seg  = t & 15;        // 16 d's per staging thread
    const int swzr = srow & 7;
    const int swzn = n16 & 7;

    const int half_ = blockIdx.x & 1;
    const int pair  = blockIdx.x >> 1;          // == batch row
    const int col   = half_*128 + wv*16 + n16;  // this lane's column
    const int tile0 = pair * ITERS;

    // ---- persistent B fragments (gamma folded in) + b1' = b1 + beta.W1 ----
    half8 Bh[8], Bl[8];
    float bsum = 0.f;
    #pragma unroll
    for (int ks = 0; ks < 8; ++ks) {
        const int k0 = ks*32 + quad*8;
        half8 h, l;
        #pragma unroll
        for (int j = 0; j < 8; ++j) {
            const float w  = w1[(size_t)(k0 + j)*H_ + col];
            bsum += beta[k0 + j] * w;
            const float wg = gamma[k0 + j] * w;
            const _Float16 hh = (_Float16)wg;
            h[j] = hh;
            l[j] = (_Float16)((wg - (float)hh) * 1024.0f);
        }
        Bh[ks] = h; Bl[ks] = l;
    }
    bsum += __shfl_xor(bsum, 16, 64);
    bsum += __shfl_xor(bsum, 32, 64);
    const float b1p = b1[col] + bsum;
    const float w20 = w2[2*col + 0];
    const float w21 = w2[2*col + 1];

    // LN (xhat only) + fp16 split + swizzled LDS store of one 32-row tile
    auto ln_stage = [&](const float* xr, char* AhW, char* AlW) {
        float s = 0.f;
        #pragma unroll
        for (int j = 0; j < 16; ++j) s += xr[j];
        s += __shfl_xor(s, 1, 64); s += __shfl_xor(s, 2, 64);
        s += __shfl_xor(s, 4, 64); s += __shfl_xor(s, 8, 64);
        const float mean = s * (1.f/256.f);
        float q = 0.f;
        #pragma unroll
        for (int j = 0; j < 16; ++j) { const float d = xr[j]-mean; q += d*d; }
        q += __shfl_xor(q, 1, 64); q += __shfl_xor(q, 2, 64);
        q += __shfl_xor(q, 4, 64); q += __shfl_xor(q, 8, 64);
        const float rstd = rsqrtf(q * (1.f/256.f) + LNEPS);
        #pragma unroll
        for (int b = 0; b < 2; ++b) {
            half8 hh, ll;
            #pragma unroll
            for (int jj = 0; jj < 8; ++jj) {
                const float x = (xr[b*8 + jj] - mean) * rstd;
                const _Float16 xh = (_Float16)x;
                hh[jj] = xh;
                ll[jj] = (_Float16)((x - (float)xh) * 1024.0f);
            }
            const int gW = ((2*seg + b) ^ swzr) * 16;
            *(half8*)(AhW + srow*512 + gW) = hh;
            *(half8*)(AlW + srow*512 + gW) = ll;
        }
    };

    // prologue: stage tile0 into buffer 0
    {
        const float* sp = slots + ((size_t)tile0*32 + srow)*D_ + seg*16;
        float xr[16];
        #pragma unroll
        for (int i4 = 0; i4 < 4; ++i4) {
            const float4 v = ((const float4*)sp)[i4];
            xr[4*i4+0]=v.x; xr[4*i4+1]=v.y; xr[4*i4+2]=v.z; xr[4*i4+3]=v.w;
        }
        ln_stage(xr, smem, smem + 16384);
    }
    __syncthreads();

    for (int i = 0; i < ITERS; ++i) {
        const int p = i & 1;
        const bool have_next = (i + 1 < ITERS);

        // prefetch next tile (global latency hidden under MFMA phase)
        float xr[16];
        if (have_next) {
            const float* sp = slots + ((size_t)(tile0+i+1)*32 + srow)*D_ + seg*16;
            #pragma unroll
            for (int i4 = 0; i4 < 4; ++i4) {
                const float4 v = ((const float4*)sp)[i4];
                xr[4*i4+0]=v.x; xr[4*i4+1]=v.y; xr[4*i4+2]=v.z; xr[4*i4+3]=v.w;
            }
        }

        // ---- MFMA: 3-pass split over K=256, 16 cols/wave ----
        const char* Ah = smem + (size_t)p*32768;
        const char* Al = Ah + 16384;
        f32x4 Ch[2], Cl[2];
        Ch[0] = (f32x4)0.f; Ch[1] = (f32x4)0.f;
        Cl[0] = (f32x4)0.f; Cl[1] = (f32x4)0.f;

        #pragma unroll
        for (int ks = 0; ks < 8; ++ks) {
            const int go = ((ks*4 + quad) ^ swzn) * 16;
            const half8 ah0 = *(const half8*)(Ah +  n16     *512 + go);
            const half8 ah1 = *(const half8*)(Ah + (n16+16) *512 + go);
            const half8 al0 = *(const half8*)(Al +  n16     *512 + go);
            const half8 al1 = *(const half8*)(Al + (n16+16) *512 + go);
            Ch[0] = __builtin_amdgcn_mfma_f32_16x16x32_f16(ah0, Bh[ks], Ch[0], 0,0,0);
            Ch[1] = __builtin_amdgcn_mfma_f32_16x16x32_f16(ah1, Bh[ks], Ch[1], 0,0,0);
            Cl[0] = __builtin_amdgcn_mfma_f32_16x16x32_f16(ah0, Bl[ks], Cl[0], 0,0,0);
            Cl[1] = __builtin_amdgcn_mfma_f32_16x16x32_f16(ah1, Bl[ks], Cl[1], 0,0,0);
            Cl[0] = __builtin_amdgcn_mfma_f32_16x16x32_f16(al0, Bh[ks], Cl[0], 0,0,0);
            Cl[1] = __builtin_amdgcn_mfma_f32_16x16x32_f16(al1, Bh[ks], Cl[1], 0,0,0);
        }

        // ---- epilogue: relu + w2, reduce over the wave's 16 cols ----
        #pragma unroll
        for (int rs = 0; rs < 2; ++rs) {
            #pragma unroll
            for (int reg = 0; reg < 4; ++reg) {
                float hv = Ch[rs][reg] + Cl[rs][reg]*INV1024 + b1p;
                hv = fmaxf(hv, 0.f);
                float p0 = hv * w20;
                float p1 = hv * w21;
                p0 += __shfl_xor(p0, 1, 64); p1 += __shfl_xor(p1, 1, 64);
                p0 += __shfl_xor(p0, 2, 64); p1 += __shfl_xor(p1, 2, 64);
                p0 += __shfl_xor(p0, 4, 64); p1 += __shfl_xor(p1, 4, 64);
                p0 += __shfl_xor(p0, 8, 64); p1 += __shfl_xor(p1, 8, 64);
                if (n16 == 0)
                    red[wv*32 + rs*16 + quad*4 + reg] = make_float2(p0, p1);
            }
        }
        __syncthreads();

        // ---- finalize: combine 8 waves -> float2 partial to ws ----
        if (t < 32) {
            float p0 = 0.f, p1 = 0.f;
            #pragma unroll
            for (int w = 0; w < 8; ++w) {
                const float2 v = red[w*32 + t];
                p0 += v.x; p1 += v.y;
            }
            const int grow = (tile0 + i)*32 + t;
            ((float2*)ws)[(size_t)half_*NROWS + grow] = make_float2(p0, p1);
        }
        // ---- stage next tile into other buffer ----
        if (have_next) {
            char* AhW = smem + (size_t)(p^1)*32768;
            ln_stage(xr, AhW, AhW + 16384);
        }
        __syncthreads();
    }
}

// Combine: one block per batch row. Sum col-half partials, gumbel decision,
// soft prob, fused lower-bound fixup (single writer per out element).
__global__ __launch_bounds__(512) void combine(
    const float* __restrict__ ws, const float* __restrict__ b2,
    const float* __restrict__ u,  const float* __restrict__ rk,
    float* __restrict__ out)
{
    __shared__ unsigned long long best[8];
    __shared__ int cnts[8];
    __shared__ int s_need, s_kbest;
    const int b = blockIdx.x;
    const int k = threadIdx.x;          // 0..511
    const int row = b*K_ + k;
    const int wv = k >> 6;

    const float2 q0 = ((const float2*)ws)[row];
    const float2 q1 = ((const float2*)ws)[NROWS + row];
    const float l0 = b2[0] + q0.x + q1.x;
    const float l1 = b2[1] + q0.y + q1.y;
    const float2 uu = ((const float2*)u)[row];
    const float g0 = -logf(-logf(uu.x));
    const float g1 = -logf(-logf(uu.y));
    const bool keep = (l1 + g1) > (l0 + g0);
    out[NROWS + row] = 1.f / (1.f + expf(l0 - l1));

    unsigned long long comb = 0;
    if (!keep)
        comb = ((unsigned long long)__float_as_uint(rk[row]) << 32)
             | (unsigned)(K_ - 1 - k);
    const int wcount = __popcll(__ballot(keep));
    #pragma unroll
    for (int off = 32; off >= 1; off >>= 1) {
        const unsigned long long o = __shfl_xor(comb, off, 64);
        if (o > comb) comb = o;
    }
    if ((k & 63) == 0) { best[wv] = comb; cnts[wv] = wcount; }
    __syncthreads();
    if (k == 0) {
        int tot = 0; unsigned long long bc = 0;
        #pragma unroll
        for (int w = 0; w < 8; ++w) { tot += cnts[w]; if (best[w] > bc) bc = best[w]; }
        s_need  = (tot == 0);
        s_kbest = (K_ - 1) - (int)(bc & 0xffffffffu);
    }
    __syncthreads();
    const bool m = keep || (s_need && (k == s_kbest));
    out[row] = m ? 1.f : 0.f;
}

extern "C" void kernel_launch(void* const* d_in, const int* in_sizes, int n_in,
                              void* d_out, int out_size, void* d_ws, size_t ws_size,
                              hipStream_t stream) {
    const float* slots = (const float*)d_in[0];
    const float* gamma = (const float*)d_in[1];
    const float* beta  = (const float*)d_in[2];
    const float* w1    = (const float*)d_in[3];
    const float* b1    = (const float*)d_in[4];
    const float* w2    = (const float*)d_in[5];
    const float* b2    = (const float*)d_in[6];
    const float* u     = (const float*)d_in[7];
    const float* rk    = (const float*)d_in[8];
    float* out = (float*)d_out;
    float* ws  = (float*)d_ws;   // 2 halves x NROWS float2 = 2 MB

    hipLaunchKernelGGL(mfma_main, dim3(512), dim3(512), LDS_BYTES, stream,
                       slots, gamma, beta, w1, b1, w2, ws);
    hipLaunchKernelGGL(combine, dim3(B_), dim3(512), 0, stream,
                       ws, b2, u, rk, out);
}

// Round 7
// 250.967 us; speedup vs baseline: 1.3105x; 1.0818x over previous
//
#include <hip/hip_runtime.h>

typedef _Float16 half8 __attribute__((ext_vector_type(8)));
typedef float f32x4 __attribute__((ext_vector_type(4)));

#define B_ 256
#define K_ 512
#define D_ 256
#define H_ 256
#define NROWS (B_*K_)          // 131072
#define LNEPS 1e-5f
#define ITERS 16               // row-tiles of 32 per block pair
#define INV1024 (1.0f/1024.0f)

// LDS A layout: per 32-row tile, arrays h and l; row stride 528 B (33x16,
// bank shift 4/row); chunk c (16B, k-range [8c,8c+8)) lives at byte offset
// pos(c)*16 where pos(c) = (c>>1) + 16*(c&1). Writes (seg-major) and reads
// (n16-major) both land on 8 distinct banks per 8-lane group.
#define ROWS_ 528
#define ASZ (32*ROWS_)          // 16896 per array
#define BUFSZ (2*ASZ)           // h + l = 33792 per buffer
#define LDS_BYTES (2*BUFSZ + 2048)   // 69632 -> 2 blocks/CU

__global__ __launch_bounds__(512, 4) void mfma_main(
    const float* __restrict__ slots, const float* __restrict__ gamma,
    const float* __restrict__ beta,  const float* __restrict__ w1,
    const float* __restrict__ b1,    const float* __restrict__ w2,
    float* __restrict__ ws)
{
    extern __shared__ __align__(16) char smem[];
    float2* red = (float2*)(smem + 2*BUFSZ);     // [8][32]

    const int t    = threadIdx.x;
    const int lane = t & 63;
    const int wv   = t >> 6;        // 0..7
    const int quad = lane >> 4;     // 0..3
    const int n16  = lane & 15;
    const int srow = t >> 4;        // 0..31 staging row
    const int seg  = t & 15;        // 16 d's per staging thread

    const int half_ = blockIdx.x & 1;
    const int pair  = blockIdx.x >> 1;          // == batch row
    const int colB  = half_*128 + wv*16 + n16;  // B-frag load column
    const int tile0 = pair * ITERS;

    // ---- persistent B fragments (gamma folded) + b1' = b1 + beta.W1 ----
    half8 Bh[8], Bl[8];
    float bsum = 0.f;
    #pragma unroll
    for (int ks = 0; ks < 8; ++ks) {
        const int k0 = ks*32 + quad*8;
        half8 h, l;
        #pragma unroll
        for (int j = 0; j < 8; ++j) {
            const float w  = w1[(size_t)(k0 + j)*H_ + colB];
            bsum += beta[k0 + j] * w;
            const float wg = gamma[k0 + j] * w;
            const _Float16 hh = (_Float16)wg;
            h[j] = hh;
            l[j] = (_Float16)((wg - (float)hh) * 1024.0f);
        }
        Bh[ks] = h; Bl[ks] = l;
    }
    bsum += __shfl_xor(bsum, 16, 64);
    bsum += __shfl_xor(bsum, 32, 64);
    const float b1col = b1[colB] + bsum;   // valid for col colB (lane n16)

    // redistribute epilogue constants to D layout: col = base + quad*4 + reg
    float b1p[4], w20[4], w21[4];
    #pragma unroll
    for (int reg = 0; reg < 4; ++reg) {
        const int cq = quad*4 + reg;                    // 0..15
        b1p[reg] = __shfl(b1col, cq, 64);               // from lane cq
        const int col = half_*128 + wv*16 + cq;
        w20[reg] = w2[2*col + 0];
        w21[reg] = w2[2*col + 1];
    }

    // LN (xhat only) + fp16 split + permuted LDS store of one 32-row tile
    auto ln_stage = [&](const float* xr, char* buf) {
        float s = 0.f;
        #pragma unroll
        for (int j = 0; j < 16; ++j) s += xr[j];
        s += __shfl_xor(s, 1, 64); s += __shfl_xor(s, 2, 64);
        s += __shfl_xor(s, 4, 64); s += __shfl_xor(s, 8, 64);
        const float mean = s * (1.f/256.f);
        float q = 0.f;
        #pragma unroll
        for (int j = 0; j < 16; ++j) { const float d = xr[j]-mean; q += d*d; }
        q += __shfl_xor(q, 1, 64); q += __shfl_xor(q, 2, 64);
        q += __shfl_xor(q, 4, 64); q += __shfl_xor(q, 8, 64);
        const float rstd = rsqrtf(q * (1.f/256.f) + LNEPS);
        char* hrow = buf        + srow*ROWS_;
        char* lrow = buf + ASZ  + srow*ROWS_;
        #pragma unroll
        for (int b = 0; b < 2; ++b) {        // chunk c = 2*seg+b, pos = seg + 16*b
            half8 hh, ll;
            #pragma unroll
            for (int jj = 0; jj < 8; ++jj) {
                const float x = (xr[b*8 + jj] - mean) * rstd;
                const _Float16 xh = (_Float16)x;
                hh[jj] = xh;
                ll[jj] = (_Float16)((x - (float)xh) * 1024.0f);
            }
            const int off = (seg + 16*b) * 16;
            *(half8*)(hrow + off) = hh;
            *(half8*)(lrow + off) = ll;
        }
    };

    // prologue: stage tile0 into buffer 0
    {
        const float* sp = slots + ((size_t)tile0*32 + srow)*D_ + seg*16;
        float xr[16];
        #pragma unroll
        for (int i4 = 0; i4 < 4; ++i4) {
            const float4 v = ((const float4*)sp)[i4];
            xr[4*i4+0]=v.x; xr[4*i4+1]=v.y; xr[4*i4+2]=v.z; xr[4*i4+3]=v.w;
        }
        ln_stage(xr, smem);
    }
    __syncthreads();

    for (int i = 0; i < ITERS; ++i) {
        const int p = i & 1;
        const bool have_next = (i + 1 < ITERS);

        // prefetch next tile (global latency hidden under MFMA phase)
        float xr[16];
        if (have_next) {
            const float* sp = slots + ((size_t)(tile0+i+1)*32 + srow)*D_ + seg*16;
            #pragma unroll
            for (int i4 = 0; i4 < 4; ++i4) {
                const float4 v = ((const float4*)sp)[i4];
                xr[4*i4+0]=v.x; xr[4*i4+1]=v.y; xr[4*i4+2]=v.z; xr[4*i4+3]=v.w;
            }
        }

        // ---- MFMA: 3-pass split over K=256, operands swapped:
        //      D[m=col(quad*4+reg)][n=slotrow(n16)] ----
        const char* Ah = smem + (size_t)p*BUFSZ;
        const char* Al = Ah + ASZ;
        f32x4 Ch[2], Cl[2];
        Ch[0] = (f32x4)0.f; Ch[1] = (f32x4)0.f;
        Cl[0] = (f32x4)0.f; Cl[1] = (f32x4)0.f;

        #pragma unroll
        for (int ks = 0; ks < 8; ++ks) {
            const int c   = ks*4 + quad;                    // chunk index
            const int off = ((c>>1) + 16*(c&1)) * 16;       // pos(c)*16
            const half8 ah0 = *(const half8*)(Ah +  n16     *ROWS_ + off);
            const half8 ah1 = *(const half8*)(Ah + (n16+16) *ROWS_ + off);
            const half8 al0 = *(const half8*)(Al +  n16     *ROWS_ + off);
            const half8 al1 = *(const half8*)(Al + (n16+16) *ROWS_ + off);
            Ch[0] = __builtin_amdgcn_mfma_f32_16x16x32_f16(Bh[ks], ah0, Ch[0], 0,0,0);
            Ch[1] = __builtin_amdgcn_mfma_f32_16x16x32_f16(Bh[ks], ah1, Ch[1], 0,0,0);
            Cl[0] = __builtin_amdgcn_mfma_f32_16x16x32_f16(Bl[ks], ah0, Cl[0], 0,0,0);
            Cl[1] = __builtin_amdgcn_mfma_f32_16x16x32_f16(Bl[ks], ah1, Cl[1], 0,0,0);
            Cl[0] = __builtin_amdgcn_mfma_f32_16x16x32_f16(Bh[ks], al0, Cl[0], 0,0,0);
            Cl[1] = __builtin_amdgcn_mfma_f32_16x16x32_f16(Bh[ks], al1, Cl[1], 0,0,0);
        }

        // ---- epilogue: relu + w2; reduce 4 regs in-register + 2 shfl ----
        #pragma unroll
        for (int rs = 0; rs < 2; ++rs) {
            float p0 = 0.f, p1 = 0.f;
            #pragma unroll
            for (int reg = 0; reg < 4; ++reg) {
                float hv = Ch[rs][reg] + Cl[rs][reg]*INV1024 + b1p[reg];
                hv = fmaxf(hv, 0.f);
                p0 = fmaf(hv, w20[reg], p0);
                p1 = fmaf(hv, w21[reg], p1);
            }
            p0 += __shfl_xor(p0, 16, 64); p1 += __shfl_xor(p1, 16, 64);
            p0 += __shfl_xor(p0, 32, 64); p1 += __shfl_xor(p1, 32, 64);
            if (lane < 16)                       // quad 0 holds the total
                red[wv*32 + rs*16 + n16] = make_float2(p0, p1);
        }
        __syncthreads();

        // ---- finalize: combine 8 waves -> float2 partial to ws ----
        if (t < 32) {
            float p0 = 0.f, p1 = 0.f;
            #pragma unroll
            for (int w = 0; w < 8; ++w) {
                const float2 v = red[w*32 + t];
                p0 += v.x; p1 += v.y;
            }
            const int grow = (tile0 + i)*32 + t;
            ((float2*)ws)[(size_t)half_*NROWS + grow] = make_float2(p0, p1);
        }
        // ---- stage next tile into other buffer ----
        if (have_next)
            ln_stage(xr, smem + (size_t)(p^1)*BUFSZ);
        __syncthreads();
    }
}

// Combine: one block per batch row. Sum col-half partials, gumbel decision,
// soft prob, fused lower-bound fixup (single writer per out element).
__global__ __launch_bounds__(512) void combine(
    const float* __restrict__ ws, const float* __restrict__ b2,
    const float* __restrict__ u,  const float* __restrict__ rk,
    float* __restrict__ out)
{
    __shared__ unsigned long long best[8];
    __shared__ int cnts[8];
    __shared__ int s_need, s_kbest;
    const int b = blockIdx.x;
    const int k = threadIdx.x;          // 0..511
    const int row = b*K_ + k;
    const int wv = k >> 6;

    const float2 q0 = ((const float2*)ws)[row];
    const float2 q1 = ((const float2*)ws)[NROWS + row];
    const float l0 = b2[0] + q0.x + q1.x;
    const float l1 = b2[1] + q0.y + q1.y;
    const float2 uu = ((const float2*)u)[row];
    const float g0 = -logf(-logf(uu.x));
    const float g1 = -logf(-logf(uu.y));
    const bool keep = (l1 + g1) > (l0 + g0);
    out[NROWS + row] = 1.f / (1.f + expf(l0 - l1));

    unsigned long long comb = 0;
    if (!keep)
        comb = ((unsigned long long)__float_as_uint(rk[row]) << 32)
             | (unsigned)(K_ - 1 - k);
    const int wcount = __popcll(__ballot(keep));
    #pragma unroll
    for (int off = 32; off >= 1; off >>= 1) {
        const unsigned long long o = __shfl_xor(comb, off, 64);
        if (o > comb) comb = o;
    }
    if ((k & 63) == 0) { best[wv] = comb; cnts[wv] = wcount; }
    __syncthreads();
    if (k == 0) {
        int tot = 0; unsigned long long bc = 0;
        #pragma unroll
        for (int w = 0; w < 8; ++w) { tot += cnts[w]; if (best[w] > bc) bc = best[w]; }
        s_need  = (tot == 0);
        s_kbest = (K_ - 1) - (int)(bc & 0xffffffffu);
    }
    __syncthreads();
    const bool m = keep || (s_need && (k == s_kbest));
    out[row] = m ? 1.f : 0.f;
}

extern "C" void kernel_launch(void* const* d_in, const int* in_sizes, int n_in,
                              void* d_out, int out_size, void* d_ws, size_t ws_size,
                              hipStream_t stream) {
    const float* slots = (const float*)d_in[0];
    const float* gamma = (const float*)d_in[1];
    const float* beta  = (const float*)d_in[2];
    const float* w1    = (const float*)d_in[3];
    const float* b1    = (const float*)d_in[4];
    const float* w2    = (const float*)d_in[5];
    const float* b2    = (const float*)d_in[6];
    const float* u     = (const float*)d_in[7];
    const float* rk    = (const float*)d_in[8];
    float* out = (float*)d_out;
    float* ws  = (float*)d_ws;   // 2 halves x NROWS float2 = 2 MB

    hipLaunchKernelGGL(mfma_main, dim3(512), dim3(512), LDS_BYTES, stream,
                       slots, gamma, beta, w1, b1, w2, ws);
    hipLaunchKernelGGL(combine, dim3(B_), dim3(512), 0, stream,
                       ws, b2, u, rk, out);
}